// Round 19
// baseline (227.536 us; speedup 1.0000x reference)
//
#include <hip/hip_runtime.h>

#define N_NODES 50000
#define N_EDGES 800000
#define EPS_BN 1e-5f
#define EBLK (N_EDGES / 128)   // 6250 edge blocks
#define NBLK ((N_NODES + 127) / 128)

// ws layout (32-bit words):
//  [0..64) sum_e [64..128) sumsq_e [128..192) scale_e [192..256) shift_e
//  [256..320) sum_n [320..384) sumsq_n [384..512) (unused)
//  [512..6656)   W_upd bf16, PRE-PERMUTED so linear global_load_lds -> swizzled LDS
//  [6656..8704)  W_gd bf16 (64x64)
//  [8704..10752) W_gs bf16 (64x64)
//  [10752..12800) W_out bf16 (64x64)
//  [12800..25300) per-node has-incoming-edge flag bytes (50000 B)
//  [25600..1625600) hbf: h as bf16 (50000 x 64) -- gather cache, 6.4 MB
// outH region (12.8 MB): phase-0 stats partials, then nstat v-spill, then final h2.
// flb ZEROING (k_pre) and flb SETTING (k_edge<0>) are separate launches (G16; r9).
// LAUNCH BOUNDS: (256,4) on phase-1/nout, (256,5) on phase-0 -- anything tighter
// spills A/e frags (r5/r7/r13/r15). PERSISTENT blocks: regression (r15).
// NT hints (r18 A/B): NT e-LOADS in phase 0 = big win (p0 ~78->~47 us: the
// once-read e stream stops evicting the hbf gather cache). NT STORES on e2/h2 =
// ~9% regression on p1 (reverted here, r19). Keep loads-NT only.

typedef __attribute__((ext_vector_type(8))) short s16x8;
typedef __attribute__((ext_vector_type(4))) float f32x4;

__device__ __forceinline__ unsigned short f2bf(float f) {
  unsigned int u = __float_as_uint(f);
  u += 0x7FFFu + ((u >> 16) & 1u);
  return (unsigned short)(u >> 16);
}
__device__ __forceinline__ unsigned int pack2(float lo, float hi) {
  return (unsigned int)f2bf(lo) | ((unsigned int)f2bf(hi) << 16);
}
__device__ __forceinline__ s16x8 cvt8(float4 a, float4 b) {
  union { s16x8 v; unsigned int u[4]; } r;
  r.u[0] = pack2(a.x, a.y); r.u[1] = pack2(a.z, a.w);
  r.u[2] = pack2(b.x, b.y); r.u[3] = pack2(b.z, b.w);
  return r.v;
}
__device__ __forceinline__ float siluf(float x) { return x / (1.f + __expf(-x)); }
__device__ __forceinline__ float4 ntload4(const float* p) {
  f32x4 v = __builtin_nontemporal_load((const f32x4*)p);
  return make_float4(v.x, v.y, v.z, v.w);
}

// ---------------- fused pre-pass: init (49 blocks) | hcvt (1563 blocks) ----------------
__global__ void k_pre(unsigned int* __restrict__ wsu,
                      const float* __restrict__ W_upd, const float* __restrict__ W_gd,
                      const float* __restrict__ W_gs, const float* __restrict__ W_out,
                      const float* __restrict__ h, short* __restrict__ hbf) {
  int b = blockIdx.x;
  if (b < 49) {
    int i = b * 256 + threadIdx.x;
    if (i < 512) wsu[i] = 0u;
    if (i < 12500) wsu[12800 + i] = 0u;   // zero flag bytes
    if (i < 6144) {
      int s = i >> 2, w = i & 3;
      int row = s / 24, slot = s - row * 24;
      int ii = slot ^ (row & 7);
      int fidx = row * 192 + ii * 8 + w * 2;
      wsu[512 + i] = pack2(W_upd[fidx], W_upd[fidx + 1]);
    }
    if (i < 2048) {
      float2 a = *(const float2*)&W_gd[(size_t)i * 2];
      float2 bb = *(const float2*)&W_gs[(size_t)i * 2];
      float2 c = *(const float2*)&W_out[(size_t)i * 2];
      wsu[6656 + i] = pack2(a.x, a.y);
      wsu[8704 + i] = pack2(bb.x, bb.y);
      wsu[10752 + i] = pack2(c.x, c.y);
    }
  } else {
    int t = (b - 49) * 256 + threadIdx.x;
    if (t < (N_NODES * 64) / 8) {
      float4 a = *(const float4*)&h[(size_t)t * 8];
      float4 bb = *(const float4*)&h[(size_t)t * 8 + 4];
      *(s16x8*)&hbf[(size_t)t * 8] = cvt8(a, bb);
    }
  }
}

// ---------------- edge kernels ----------------
// PHASE 0: stats partials (+flag setting).  grid = EBLK.
// PHASE 1: e2 output; blocks >= EBLK run the independent node-stats body.
//          grid = EBLK + NBLK.
template<int PHASE>
__global__ __launch_bounds__(256, PHASE == 0 ? 5 : 4) void k_edge(
    const short* __restrict__ hbf, const float* __restrict__ e,
    const int* __restrict__ src, const int* __restrict__ dst,
    const unsigned int* __restrict__ wsu, const float* __restrict__ b_upd,
    const float* __restrict__ ws, unsigned char* __restrict__ flb,
    const float* __restrict__ b_gd, const float* __restrict__ b_gs,
    float* __restrict__ wsm, float* __restrict__ v_out,
    float* __restrict__ out_e)
{
  __shared__ short Bls[64 * 192];   // W_upd tile (edge path) / Bgd|Bgs (nstat path)
  __shared__ float red[4][128];

  int tid = threadIdx.x;
  int ln = tid & 63, wv = tid >> 6;
  int lr = ln & 15, lq = ln >> 4, lk = lq * 8;

  if (PHASE == 1 && blockIdx.x >= EBLK) {
    // ================= nstat body: v = hgs + fl*hgd; spill v; sum/sumsq =================
    short* Bgd = Bls;
    short* Bgs = Bls + 4096;
    const uint4* Sgd = (const uint4*)(wsu + 6656);
    const uint4* Sgs = (const uint4*)(wsu + 8704);
    #pragma unroll
    for (int j = 0; j < 2; ++j) {
      int c = tid + j * 256;
      int row = c >> 3, i = c & 7, sl = row * 8 + (i ^ (row & 7));
      ((uint4*)Bgd)[sl] = Sgd[c];
      ((uint4*)Bgs)[sl] = Sgs[c];
    }
    int n0 = (blockIdx.x - EBLK) * 128;
    int r0 = wv * 32 + lr, r1 = r0 + 16;
    int nA = min(n0 + r0, N_NODES - 1), nB = min(n0 + r1, N_NODES - 1);
    s16x8 A0[2], A1[2];
    A0[0] = *(const s16x8*)&hbf[nA * 64 + lk];
    A0[1] = *(const s16x8*)&hbf[nA * 64 + 32 + lk];
    A1[0] = *(const s16x8*)&hbf[nB * 64 + lk];
    A1[1] = *(const s16x8*)&hbf[nB * 64 + 32 + lk];
    __syncthreads();

    f32x4 zero4 = {0.f, 0.f, 0.f, 0.f};
    f32x4 accd[2][4], accs[2][4];
    #pragma unroll
    for (int rt = 0; rt < 2; ++rt)
      #pragma unroll
      for (int ct = 0; ct < 4; ++ct) { accd[rt][ct] = zero4; accs[rt][ct] = zero4; }
    #pragma unroll
    for (int ct = 0; ct < 4; ++ct) {
      int row = ct * 16 + lr, r7 = row & 7;
      #pragma unroll
      for (int kk = 0; kk < 2; ++kk) {
        int sl = ((kk * 4 + lq) ^ r7) << 3;
        s16x8 bd = *(const s16x8*)&Bgd[row * 64 + sl];
        s16x8 bs = *(const s16x8*)&Bgs[row * 64 + sl];
        accd[0][ct] = __builtin_amdgcn_mfma_f32_16x16x32_bf16(A0[kk], bd, accd[0][ct], 0, 0, 0);
        accd[1][ct] = __builtin_amdgcn_mfma_f32_16x16x32_bf16(A1[kk], bd, accd[1][ct], 0, 0, 0);
        accs[0][ct] = __builtin_amdgcn_mfma_f32_16x16x32_bf16(A0[kk], bs, accs[0][ct], 0, 0, 0);
        accs[1][ct] = __builtin_amdgcn_mfma_f32_16x16x32_bf16(A1[kk], bs, accs[1][ct], 0, 0, 0);
      }
    }
    float s1[4], s2[4];
    #pragma unroll
    for (int ct = 0; ct < 4; ++ct) {
      int col = ct * 16 + lr;
      float bd = b_gd[col], bs = b_gs[col];
      float a1s = 0.f, a2s = 0.f;
      #pragma unroll
      for (int rt = 0; rt < 2; ++rt)
        #pragma unroll
        for (int q = 0; q < 4; ++q) {
          int row = wv * 32 + rt * 16 + lq * 4 + q;
          int n = n0 + row;
          if (n < N_NODES) {
            float fl = (float)flb[n];
            float v = accs[rt][ct][q] + bs + fl * (accd[rt][ct][q] + bd);
            v_out[(size_t)n * 64 + col] = v;
            a1s += v; a2s += v * v;
          }
        }
      s1[ct] = a1s; s2[ct] = a2s;
    }
    #pragma unroll
    for (int ct = 0; ct < 4; ++ct) {
      s1[ct] += __shfl_xor(s1[ct], 16); s1[ct] += __shfl_xor(s1[ct], 32);
      s2[ct] += __shfl_xor(s2[ct], 16); s2[ct] += __shfl_xor(s2[ct], 32);
    }
    if (ln < 16) {
      #pragma unroll
      for (int ct = 0; ct < 4; ++ct) {
        red[wv][ct * 16 + ln] = s1[ct];
        red[wv][64 + ct * 16 + ln] = s2[ct];
      }
    }
    __syncthreads();
    if (tid < 128) {
      float t = red[0][tid] + red[1][tid] + red[2][tid] + red[3][tid];
      atomicAdd(&wsm[256 + tid], t);
    }
    return;
  }

  // ================= edge body =================
  int m0 = blockIdx.x * 128;
  int r0 = wv * 32 + lr, r1 = r0 + 16;
  int mA = m0 + r0, mB = m0 + r1;

  // 1. e loads (HBM, independent).  Phase 0 reads e exactly once -> non-temporal
  //    (protects hbf residency in L2/L3).  Phase 1 keeps them cached: the epre
  //    residual reads below hit the same lines.
  const float* pe0 = e + (size_t)mA * 64 + lk;
  const float* pe1 = e + (size_t)mB * 64 + lk;
  float4 e0a, e0b, e0c, e0d, e1a, e1b, e1c, e1d;
  if (PHASE == 0) {
    e0a = ntload4(pe0);      e0b = ntload4(pe0 + 4);
    e0c = ntload4(pe0 + 32); e0d = ntload4(pe0 + 36);
    e1a = ntload4(pe1);      e1b = ntload4(pe1 + 4);
    e1c = ntload4(pe1 + 32); e1d = ntload4(pe1 + 36);
  } else {
    e0a = *(const float4*)(pe0);      e0b = *(const float4*)(pe0 + 4);
    e0c = *(const float4*)(pe0 + 32); e0d = *(const float4*)(pe0 + 36);
    e1a = *(const float4*)(pe1);      e1b = *(const float4*)(pe1 + 4);
    e1c = *(const float4*)(pe1 + 32); e1d = *(const float4*)(pe1 + 36);
  }

  // 2. indices
  int s0 = src[mA], d0 = dst[mA];
  int s1i = src[mB], d1 = dst[mB];

  // phase 0: flag-setting fused here (idempotent byte stores; zeroing in k_pre launch)
  if (PHASE == 0 && lq == 0) { flb[d0] = 1; flb[d1] = 1; }

  // 3. A-gathers: 8 independent 16B bf16 loads
  s16x8 A0[6], A1[6];
  A0[0] = *(const s16x8*)&hbf[s0 * 64 + lk];
  A0[1] = *(const s16x8*)&hbf[s0 * 64 + 32 + lk];
  A0[2] = *(const s16x8*)&hbf[d0 * 64 + lk];
  A0[3] = *(const s16x8*)&hbf[d0 * 64 + 32 + lk];
  A1[0] = *(const s16x8*)&hbf[s1i * 64 + lk];
  A1[1] = *(const s16x8*)&hbf[s1i * 64 + 32 + lk];
  A1[2] = *(const s16x8*)&hbf[d1 * 64 + lk];
  A1[3] = *(const s16x8*)&hbf[d1 * 64 + 32 + lk];

  // 4. B staging: async global->LDS, zero VGPR
  {
    unsigned int* bls32 = (unsigned int*)Bls;
    #pragma unroll
    for (int j = 0; j < 6; ++j) {
      int base = (j * 4 + wv) * 256;   // word offset, wave-uniform
      __builtin_amdgcn_global_load_lds(
          (__attribute__((address_space(1))) void*)(unsigned int*)(wsu + 512 + base + ln * 4),
          (__attribute__((address_space(3))) void*)(bls32 + base),
          16, 0, 0);
    }
  }

  // 5. pack e -> bf16 frags
  A0[4] = cvt8(e0a, e0b);
  A0[5] = cvt8(e0c, e0d);
  A1[4] = cvt8(e1a, e1b);
  A1[5] = cvt8(e1c, e1d);
  __syncthreads();   // drains vmcnt (incl. global_load_lds) + barrier

  // phase 1: residual prefetch issued before MFMA (L2-hit, flies under compute)
  int rl = ln >> 4, c0 = (ln & 15) * 4;
  float4 epre[2][4];
  if (PHASE == 1) {
    #pragma unroll
    for (int rt = 0; rt < 2; ++rt)
      #pragma unroll
      for (int q = 0; q < 4; ++q)
        epre[rt][q] = *(const float4*)&e[(size_t)(m0 + wv * 32 + rt * 16 + rl * 4 + q) * 64 + c0];
  }

  f32x4 zero4 = {0.f, 0.f, 0.f, 0.f};
  f32x4 acc[2][4];
  #pragma unroll
  for (int rt = 0; rt < 2; ++rt)
    #pragma unroll
    for (int ct = 0; ct < 4; ++ct) acc[rt][ct] = zero4;

  #pragma unroll
  for (int ct = 0; ct < 4; ++ct) {
    int row = ct * 16 + lr, r7 = row & 7;
    #pragma unroll
    for (int kk = 0; kk < 6; ++kk) {
      s16x8 b = *(const s16x8*)&Bls[row * 192 + (((kk * 4 + lq) ^ r7) << 3)];
      acc[0][ct] = __builtin_amdgcn_mfma_f32_16x16x32_bf16(A0[kk], b, acc[0][ct], 0, 0, 0);
      acc[1][ct] = __builtin_amdgcn_mfma_f32_16x16x32_bf16(A1[kk], b, acc[1][ct], 0, 0, 0);
    }
  }

  if (PHASE == 0) {
    // per-block stats partials -> out_e (= outH scratch), NO global atomics
    float s1[4], s2[4];
    #pragma unroll
    for (int ct = 0; ct < 4; ++ct) {
      float bias = b_upd[ct * 16 + lr];
      float a1s = 0.f, a2s = 0.f;
      #pragma unroll
      for (int rt = 0; rt < 2; ++rt)
        #pragma unroll
        for (int q = 0; q < 4; ++q) {
          float v = acc[rt][ct][q] + bias;
          a1s += v; a2s += v * v;
        }
      s1[ct] = a1s; s2[ct] = a2s;
    }
    #pragma unroll
    for (int ct = 0; ct < 4; ++ct) {
      s1[ct] += __shfl_xor(s1[ct], 16); s1[ct] += __shfl_xor(s1[ct], 32);
      s2[ct] += __shfl_xor(s2[ct], 16); s2[ct] += __shfl_xor(s2[ct], 32);
    }
    if (ln < 16) {
      #pragma unroll
      for (int ct = 0; ct < 4; ++ct) {
        red[wv][ct * 16 + ln] = s1[ct];
        red[wv][64 + ct * 16 + ln] = s2[ct];
      }
    }
    __syncthreads();
    if (tid < 128) {
      float t = red[0][tid] + red[1][tid] + red[2][tid] + red[3][tid];
      out_e[(size_t)blockIdx.x * 128 + tid] = t;
    }
  } else {
    // bn+silu in frag layout (in place)
    #pragma unroll
    for (int ct = 0; ct < 4; ++ct) {
      int col = ct * 16 + lr;
      float scale = ws[128 + col], shift = ws[192 + col], bias = b_upd[col];
      #pragma unroll
      for (int rt = 0; rt < 2; ++rt)
        #pragma unroll
        for (int q = 0; q < 4; ++q) {
          float x = acc[rt][ct][q] + bias;
          acc[rt][ct][q] = siluf(x * scale + shift);
        }
    }
    __syncthreads();   // all waves done reading Bls -> reuse as transpose scratch
    float* T = (float*)((char*)Bls + wv * 1280);   // 4 rows x 72-float stride
    #pragma unroll
    for (int rt = 0; rt < 2; ++rt) {
      #pragma unroll
      for (int q = 0; q < 4; ++q) {
        #pragma unroll
        for (int ct = 0; ct < 4; ++ct)
          T[lq * 72 + ct * 16 + lr] = acc[rt][ct][q];
        float4 t4 = *(const float4*)&T[rl * 72 + c0];
        float4 ev = epre[rt][q];
        t4.x += ev.x; t4.y += ev.y; t4.z += ev.z; t4.w += ev.w;
        *(float4*)&out_e[(size_t)(m0 + wv * 32 + rt * 16 + rl * 4 + q) * 64 + c0] = t4;
      }
    }
  }
}

// ---------------- fused reduce + finalize edge-BN stats: 64 blocks, one per feature ----------------
__global__ void k_redfin(const float* __restrict__ partials, float* __restrict__ ws,
                         const float* __restrict__ gamma, const float* __restrict__ beta,
                         float rcount) {
  __shared__ float sr[2][256];
  int c = blockIdx.x;   // 0..63
  float s1 = 0.f, s2 = 0.f;
  for (int i = threadIdx.x; i < EBLK; i += 256) {
    s1 += partials[(size_t)i * 128 + c];
    s2 += partials[(size_t)i * 128 + 64 + c];
  }
  sr[0][threadIdx.x] = s1; sr[1][threadIdx.x] = s2;
  __syncthreads();
  for (int off = 128; off >= 1; off >>= 1) {
    if (threadIdx.x < off) {
      sr[0][threadIdx.x] += sr[0][threadIdx.x + off];
      sr[1][threadIdx.x] += sr[1][threadIdx.x + off];
    }
    __syncthreads();
  }
  if (threadIdx.x == 0) {
    float mean = sr[0][0] * rcount;
    float var = sr[1][0] * rcount - mean * mean;
    float a = rsqrtf(var + EPS_BN) * gamma[c];
    ws[128 + c] = a;
    ws[192 + c] = beta[c] - mean * a;
  }
}

// ---------------- node output: inline BN-finalize; t = silu(bn(v)) + h; out = t@W_out.T + b ----------------
__global__ __launch_bounds__(256, 4) void k_nout(
    const float* __restrict__ h, const unsigned int* __restrict__ wsu,
    const float* __restrict__ g_gn, const float* __restrict__ be_gn,
    const float* __restrict__ b_out, const float* __restrict__ ws,
    const float* __restrict__ v_in, float* __restrict__ out_h)
{
  __shared__ short R1[128 * 64];   // t-tile, swizzled
  __shared__ short R2[64 * 64];    // W_out, swizzled
  __shared__ float sA[64], sB[64];
  int tid = threadIdx.x;
  int ln = tid & 63, wv = tid >> 6;
  int lr = ln & 15, lq = ln >> 4;
  int n0 = blockIdx.x * 128;

  const uint4* Sot = (const uint4*)(wsu + 10752);
  #pragma unroll
  for (int j = 0; j < 2; ++j) {
    int c = tid + j * 256;
    int row = c >> 3, i = c & 7, sl = row * 8 + (i ^ (row & 7));
    ((uint4*)R2)[sl] = Sot[c];
  }
  // inline finalize of node BN scale/shift (redundant per block, cheap)
  if (tid < 64) {
    float mean = ws[256 + tid] * (1.f / (float)N_NODES);
    float var = ws[320 + tid] * (1.f / (float)N_NODES) - mean * mean;
    float a = rsqrtf(var + EPS_BN) * g_gn[tid];
    sA[tid] = a;
    sB[tid] = be_gn[tid] - mean * a;
  }
  __syncthreads();

  // row-layout: coalesced float4 reads of v and h; BN+silu+residual; bf16 into R1
  int c0 = (tid & 15) * 4;
  int rbase = tid >> 4;   // 0..15
  float4 scl = *(const float4*)&sA[c0];
  float4 shf = *(const float4*)&sB[c0];
  #pragma unroll
  for (int i = 0; i < 8; ++i) {
    int row = rbase + 16 * i;
    int n = min(n0 + row, N_NODES - 1);
    float4 v4 = *(const float4*)&v_in[(size_t)n * 64 + c0];
    float4 h4 = *(const float4*)&h[(size_t)n * 64 + c0];
    float tx = siluf(v4.x * scl.x + shf.x) + h4.x;
    float ty = siluf(v4.y * scl.y + shf.y) + h4.y;
    float tz = siluf(v4.z * scl.z + shf.z) + h4.z;
    float tw = siluf(v4.w * scl.w + shf.w) + h4.w;
    int sl = ((((c0 >> 3) ^ (row & 7)) << 3) | (c0 & 7));
    unsigned int* p = (unsigned int*)&R1[row * 64 + sl];
    p[0] = pack2(tx, ty);
    p[1] = pack2(tz, tw);
  }
  __syncthreads();

  int r0 = wv * 32 + lr, r1 = r0 + 16;
  s16x8 T0[2], T1[2];
  #pragma unroll
  for (int kk = 0; kk < 2; ++kk) {
    T0[kk] = *(const s16x8*)&R1[r0 * 64 + (((kk * 4 + lq) ^ (r0 & 7)) << 3)];
    T1[kk] = *(const s16x8*)&R1[r1 * 64 + (((kk * 4 + lq) ^ (r1 & 7)) << 3)];
  }
  f32x4 zero4 = {0.f, 0.f, 0.f, 0.f};
  f32x4 ac2[2][4];
  #pragma unroll
  for (int rt = 0; rt < 2; ++rt)
    #pragma unroll
    for (int ct = 0; ct < 4; ++ct) ac2[rt][ct] = zero4;
  #pragma unroll
  for (int ct = 0; ct < 4; ++ct) {
    int row = ct * 16 + lr, r7 = row & 7;
    #pragma unroll
    for (int kk = 0; kk < 2; ++kk) {
      s16x8 b = *(const s16x8*)&R2[row * 64 + (((kk * 4 + lq) ^ r7) << 3)];
      ac2[0][ct] = __builtin_amdgcn_mfma_f32_16x16x32_bf16(T0[kk], b, ac2[0][ct], 0, 0, 0);
      ac2[1][ct] = __builtin_amdgcn_mfma_f32_16x16x32_bf16(T1[kk], b, ac2[1][ct], 0, 0, 0);
    }
  }
  #pragma unroll
  for (int ct = 0; ct < 4; ++ct) {
    int col = ct * 16 + lr;
    float bo = b_out[col];
    #pragma unroll
    for (int rt = 0; rt < 2; ++rt)
      #pragma unroll
      for (int q = 0; q < 4; ++q) {
        int row = wv * 32 + rt * 16 + lq * 4 + q;
        int n = n0 + row;
        if (n < N_NODES) out_h[(size_t)n * 64 + col] = ac2[rt][ct][q] + bo;
      }
  }
}

extern "C" void kernel_launch(void* const* d_in, const int* in_sizes, int n_in,
                              void* d_out, int out_size, void* d_ws, size_t ws_size,
                              hipStream_t stream) {
  const float* h     = (const float*)d_in[0];
  const float* e     = (const float*)d_in[1];
  const int*   src   = (const int*)d_in[2];
  const int*   dst   = (const int*)d_in[3];
  const float* W_upd = (const float*)d_in[4];
  const float* b_upd = (const float*)d_in[5];
  const float* g_un  = (const float*)d_in[6];
  const float* be_un = (const float*)d_in[7];
  // d_in[8], d_in[9]: W_act, b_act -- dead (softmax weights sum to 1 per dst)
  const float* W_gd  = (const float*)d_in[10];
  const float* b_gd  = (const float*)d_in[11];
  const float* W_gs  = (const float*)d_in[12];
  const float* b_gs  = (const float*)d_in[13];
  const float* g_gn  = (const float*)d_in[14];
  const float* be_gn = (const float*)d_in[15];
  const float* W_out = (const float*)d_in[16];
  const float* b_out = (const float*)d_in[17];

  float* outH = (float*)d_out;
  float* outE = outH + (size_t)N_NODES * 64;
  float* ws = (float*)d_ws;
  unsigned int* wsu = (unsigned int*)d_ws;
  unsigned char* flb = (unsigned char*)(wsu + 12800);
  short* hbf = (short*)(wsu + 25600);

  // 1. init + h->bf16 cache
  k_pre<<<49 + 1563, 256, 0, stream>>>(wsu, W_upd, W_gd, W_gs, W_out, h, hbf);
  // 2. edge GEMM phase 0: stats partials -> outH scratch; sets flags
  k_edge<0><<<EBLK, 256, 0, stream>>>(hbf, e, src, dst, wsu, b_upd, ws, flb,
                                      nullptr, nullptr, nullptr, nullptr, outH);
  // 3. reduce+finalize edge BN
  k_redfin<<<64, 256, 0, stream>>>(outH, ws, g_un, be_un, 1.f / (float)N_EDGES);
  // 4. edge GEMM phase 1 (e2 output) + riding nstat blocks (v-spill -> outH, node sums)
  k_edge<1><<<EBLK + NBLK, 256, 0, stream>>>(hbf, e, src, dst, wsu, b_upd, ws, flb,
                                             b_gd, b_gs, ws, outH, outE);
  // 5. node output (inline BN finalize)
  k_nout<<<NBLK, 256, 0, stream>>>(h, wsu, g_gn, be_gn, b_out, ws, outH, outH);
}

// Round 20
// 218.145 us; speedup vs baseline: 1.0430x; 1.0430x over previous
//
#include <hip/hip_runtime.h>

#define N_NODES 50000
#define N_EDGES 800000
#define EPS_BN 1e-5f
#define EBLK (N_EDGES / 128)   // 6250 edge blocks
#define NBLK ((N_NODES + 127) / 128)

// ws layout (32-bit words):
//  [0..64) sum_e [64..128) sumsq_e [128..192) scale_e [192..256) shift_e
//  [256..320) sum_n [320..384) sumsq_n [384..512) (unused)
//  [512..6656)   W_upd bf16, PRE-PERMUTED so linear global_load_lds -> swizzled LDS
//  [6656..8704)  W_gd bf16 (64x64)
//  [8704..10752) W_gs bf16 (64x64)
//  [10752..12800) W_out bf16 (64x64)
//  [12800..25300) per-node has-incoming-edge flag bytes (50000 B)
//  [25600..1625600) hbf: h as bf16 (50000 x 64) -- gather cache, 6.4 MB
// outH region (12.8 MB): phase-0 stats partials, then nstat v-spill, then final h2.
// flb ZEROING (k_pre) and flb SETTING (k_edge<0>) are separate launches (G16; r9).
// LAUNCH BOUNDS: (256,4) on phase-1/nout, (256,5) on phase-0 -- anything tighter
// spills A/e frags (r5/r7/r13/r15). PERSISTENT blocks: regression (r15).
// NT hints (r16/r18/r19 A/B/A): BOTH NT e-loads (p0) AND NT stores (e2, h2)
// are wins -- r16 no-NT 228.7, r18 both-NT 219.1, r19 loads-only 227.5.
// The never-re-read streams must not allocate in L2/L3 so the hbf gather
// cache stays resident.  This file = r18 configuration (best measured).

typedef __attribute__((ext_vector_type(8))) short s16x8;
typedef __attribute__((ext_vector_type(4))) float f32x4;

__device__ __forceinline__ unsigned short f2bf(float f) {
  unsigned int u = __float_as_uint(f);
  u += 0x7FFFu + ((u >> 16) & 1u);
  return (unsigned short)(u >> 16);
}
__device__ __forceinline__ unsigned int pack2(float lo, float hi) {
  return (unsigned int)f2bf(lo) | ((unsigned int)f2bf(hi) << 16);
}
__device__ __forceinline__ s16x8 cvt8(float4 a, float4 b) {
  union { s16x8 v; unsigned int u[4]; } r;
  r.u[0] = pack2(a.x, a.y); r.u[1] = pack2(a.z, a.w);
  r.u[2] = pack2(b.x, b.y); r.u[3] = pack2(b.z, b.w);
  return r.v;
}
__device__ __forceinline__ float siluf(float x) { return x / (1.f + __expf(-x)); }
__device__ __forceinline__ float4 ntload4(const float* p) {
  f32x4 v = __builtin_nontemporal_load((const f32x4*)p);
  return make_float4(v.x, v.y, v.z, v.w);
}
__device__ __forceinline__ void ntstore4(float* p, float4 v) {
  f32x4 t = {v.x, v.y, v.z, v.w};
  __builtin_nontemporal_store(t, (f32x4*)p);
}

// ---------------- fused pre-pass: init (49 blocks) | hcvt (1563 blocks) ----------------
__global__ void k_pre(unsigned int* __restrict__ wsu,
                      const float* __restrict__ W_upd, const float* __restrict__ W_gd,
                      const float* __restrict__ W_gs, const float* __restrict__ W_out,
                      const float* __restrict__ h, short* __restrict__ hbf) {
  int b = blockIdx.x;
  if (b < 49) {
    int i = b * 256 + threadIdx.x;
    if (i < 512) wsu[i] = 0u;
    if (i < 12500) wsu[12800 + i] = 0u;   // zero flag bytes
    if (i < 6144) {
      int s = i >> 2, w = i & 3;
      int row = s / 24, slot = s - row * 24;
      int ii = slot ^ (row & 7);
      int fidx = row * 192 + ii * 8 + w * 2;
      wsu[512 + i] = pack2(W_upd[fidx], W_upd[fidx + 1]);
    }
    if (i < 2048) {
      float2 a = *(const float2*)&W_gd[(size_t)i * 2];
      float2 bb = *(const float2*)&W_gs[(size_t)i * 2];
      float2 c = *(const float2*)&W_out[(size_t)i * 2];
      wsu[6656 + i] = pack2(a.x, a.y);
      wsu[8704 + i] = pack2(bb.x, bb.y);
      wsu[10752 + i] = pack2(c.x, c.y);
    }
  } else {
    int t = (b - 49) * 256 + threadIdx.x;
    if (t < (N_NODES * 64) / 8) {
      float4 a = *(const float4*)&h[(size_t)t * 8];
      float4 bb = *(const float4*)&h[(size_t)t * 8 + 4];
      *(s16x8*)&hbf[(size_t)t * 8] = cvt8(a, bb);
    }
  }
}

// ---------------- edge kernels ----------------
// PHASE 0: stats partials (+flag setting).  grid = EBLK.
// PHASE 1: e2 output; blocks >= EBLK run the independent node-stats body.
//          grid = EBLK + NBLK.
template<int PHASE>
__global__ __launch_bounds__(256, PHASE == 0 ? 5 : 4) void k_edge(
    const short* __restrict__ hbf, const float* __restrict__ e,
    const int* __restrict__ src, const int* __restrict__ dst,
    const unsigned int* __restrict__ wsu, const float* __restrict__ b_upd,
    const float* __restrict__ ws, unsigned char* __restrict__ flb,
    const float* __restrict__ b_gd, const float* __restrict__ b_gs,
    float* __restrict__ wsm, float* __restrict__ v_out,
    float* __restrict__ out_e)
{
  __shared__ short Bls[64 * 192];   // W_upd tile (edge path) / Bgd|Bgs (nstat path)
  __shared__ float red[4][128];

  int tid = threadIdx.x;
  int ln = tid & 63, wv = tid >> 6;
  int lr = ln & 15, lq = ln >> 4, lk = lq * 8;

  if (PHASE == 1 && blockIdx.x >= EBLK) {
    // ================= nstat body: v = hgs + fl*hgd; spill v; sum/sumsq =================
    short* Bgd = Bls;
    short* Bgs = Bls + 4096;
    const uint4* Sgd = (const uint4*)(wsu + 6656);
    const uint4* Sgs = (const uint4*)(wsu + 8704);
    #pragma unroll
    for (int j = 0; j < 2; ++j) {
      int c = tid + j * 256;
      int row = c >> 3, i = c & 7, sl = row * 8 + (i ^ (row & 7));
      ((uint4*)Bgd)[sl] = Sgd[c];
      ((uint4*)Bgs)[sl] = Sgs[c];
    }
    int n0 = (blockIdx.x - EBLK) * 128;
    int r0 = wv * 32 + lr, r1 = r0 + 16;
    int nA = min(n0 + r0, N_NODES - 1), nB = min(n0 + r1, N_NODES - 1);
    s16x8 A0[2], A1[2];
    A0[0] = *(const s16x8*)&hbf[nA * 64 + lk];
    A0[1] = *(const s16x8*)&hbf[nA * 64 + 32 + lk];
    A1[0] = *(const s16x8*)&hbf[nB * 64 + lk];
    A1[1] = *(const s16x8*)&hbf[nB * 64 + 32 + lk];
    __syncthreads();

    f32x4 zero4 = {0.f, 0.f, 0.f, 0.f};
    f32x4 accd[2][4], accs[2][4];
    #pragma unroll
    for (int rt = 0; rt < 2; ++rt)
      #pragma unroll
      for (int ct = 0; ct < 4; ++ct) { accd[rt][ct] = zero4; accs[rt][ct] = zero4; }
    #pragma unroll
    for (int ct = 0; ct < 4; ++ct) {
      int row = ct * 16 + lr, r7 = row & 7;
      #pragma unroll
      for (int kk = 0; kk < 2; ++kk) {
        int sl = ((kk * 4 + lq) ^ r7) << 3;
        s16x8 bd = *(const s16x8*)&Bgd[row * 64 + sl];
        s16x8 bs = *(const s16x8*)&Bgs[row * 64 + sl];
        accd[0][ct] = __builtin_amdgcn_mfma_f32_16x16x32_bf16(A0[kk], bd, accd[0][ct], 0, 0, 0);
        accd[1][ct] = __builtin_amdgcn_mfma_f32_16x16x32_bf16(A1[kk], bd, accd[1][ct], 0, 0, 0);
        accs[0][ct] = __builtin_amdgcn_mfma_f32_16x16x32_bf16(A0[kk], bs, accs[0][ct], 0, 0, 0);
        accs[1][ct] = __builtin_amdgcn_mfma_f32_16x16x32_bf16(A1[kk], bs, accs[1][ct], 0, 0, 0);
      }
    }
    float s1[4], s2[4];
    #pragma unroll
    for (int ct = 0; ct < 4; ++ct) {
      int col = ct * 16 + lr;
      float bd = b_gd[col], bs = b_gs[col];
      float a1s = 0.f, a2s = 0.f;
      #pragma unroll
      for (int rt = 0; rt < 2; ++rt)
        #pragma unroll
        for (int q = 0; q < 4; ++q) {
          int row = wv * 32 + rt * 16 + lq * 4 + q;
          int n = n0 + row;
          if (n < N_NODES) {
            float fl = (float)flb[n];
            float v = accs[rt][ct][q] + bs + fl * (accd[rt][ct][q] + bd);
            v_out[(size_t)n * 64 + col] = v;
            a1s += v; a2s += v * v;
          }
        }
      s1[ct] = a1s; s2[ct] = a2s;
    }
    #pragma unroll
    for (int ct = 0; ct < 4; ++ct) {
      s1[ct] += __shfl_xor(s1[ct], 16); s1[ct] += __shfl_xor(s1[ct], 32);
      s2[ct] += __shfl_xor(s2[ct], 16); s2[ct] += __shfl_xor(s2[ct], 32);
    }
    if (ln < 16) {
      #pragma unroll
      for (int ct = 0; ct < 4; ++ct) {
        red[wv][ct * 16 + ln] = s1[ct];
        red[wv][64 + ct * 16 + ln] = s2[ct];
      }
    }
    __syncthreads();
    if (tid < 128) {
      float t = red[0][tid] + red[1][tid] + red[2][tid] + red[3][tid];
      atomicAdd(&wsm[256 + tid], t);
    }
    return;
  }

  // ================= edge body =================
  int m0 = blockIdx.x * 128;
  int r0 = wv * 32 + lr, r1 = r0 + 16;
  int mA = m0 + r0, mB = m0 + r1;

  // 1. e loads (HBM, independent).  Phase 0 reads e exactly once -> non-temporal
  //    (protects hbf residency in L2/L3).  Phase 1 keeps them cached: the epre
  //    residual reads below hit the same lines.
  const float* pe0 = e + (size_t)mA * 64 + lk;
  const float* pe1 = e + (size_t)mB * 64 + lk;
  float4 e0a, e0b, e0c, e0d, e1a, e1b, e1c, e1d;
  if (PHASE == 0) {
    e0a = ntload4(pe0);      e0b = ntload4(pe0 + 4);
    e0c = ntload4(pe0 + 32); e0d = ntload4(pe0 + 36);
    e1a = ntload4(pe1);      e1b = ntload4(pe1 + 4);
    e1c = ntload4(pe1 + 32); e1d = ntload4(pe1 + 36);
  } else {
    e0a = *(const float4*)(pe0);      e0b = *(const float4*)(pe0 + 4);
    e0c = *(const float4*)(pe0 + 32); e0d = *(const float4*)(pe0 + 36);
    e1a = *(const float4*)(pe1);      e1b = *(const float4*)(pe1 + 4);
    e1c = *(const float4*)(pe1 + 32); e1d = *(const float4*)(pe1 + 36);
  }

  // 2. indices
  int s0 = src[mA], d0 = dst[mA];
  int s1i = src[mB], d1 = dst[mB];

  // phase 0: flag-setting fused here (idempotent byte stores; zeroing in k_pre launch)
  if (PHASE == 0 && lq == 0) { flb[d0] = 1; flb[d1] = 1; }

  // 3. A-gathers: 8 independent 16B bf16 loads
  s16x8 A0[6], A1[6];
  A0[0] = *(const s16x8*)&hbf[s0 * 64 + lk];
  A0[1] = *(const s16x8*)&hbf[s0 * 64 + 32 + lk];
  A0[2] = *(const s16x8*)&hbf[d0 * 64 + lk];
  A0[3] = *(const s16x8*)&hbf[d0 * 64 + 32 + lk];
  A1[0] = *(const s16x8*)&hbf[s1i * 64 + lk];
  A1[1] = *(const s16x8*)&hbf[s1i * 64 + 32 + lk];
  A1[2] = *(const s16x8*)&hbf[d1 * 64 + lk];
  A1[3] = *(const s16x8*)&hbf[d1 * 64 + 32 + lk];

  // 4. B staging: async global->LDS, zero VGPR
  {
    unsigned int* bls32 = (unsigned int*)Bls;
    #pragma unroll
    for (int j = 0; j < 6; ++j) {
      int base = (j * 4 + wv) * 256;   // word offset, wave-uniform
      __builtin_amdgcn_global_load_lds(
          (__attribute__((address_space(1))) void*)(unsigned int*)(wsu + 512 + base + ln * 4),
          (__attribute__((address_space(3))) void*)(bls32 + base),
          16, 0, 0);
    }
  }

  // 5. pack e -> bf16 frags
  A0[4] = cvt8(e0a, e0b);
  A0[5] = cvt8(e0c, e0d);
  A1[4] = cvt8(e1a, e1b);
  A1[5] = cvt8(e1c, e1d);
  __syncthreads();   // drains vmcnt (incl. global_load_lds) + barrier

  // phase 1: residual prefetch issued before MFMA (L2-hit, flies under compute)
  int rl = ln >> 4, c0 = (ln & 15) * 4;
  float4 epre[2][4];
  if (PHASE == 1) {
    #pragma unroll
    for (int rt = 0; rt < 2; ++rt)
      #pragma unroll
      for (int q = 0; q < 4; ++q)
        epre[rt][q] = *(const float4*)&e[(size_t)(m0 + wv * 32 + rt * 16 + rl * 4 + q) * 64 + c0];
  }

  f32x4 zero4 = {0.f, 0.f, 0.f, 0.f};
  f32x4 acc[2][4];
  #pragma unroll
  for (int rt = 0; rt < 2; ++rt)
    #pragma unroll
    for (int ct = 0; ct < 4; ++ct) acc[rt][ct] = zero4;

  #pragma unroll
  for (int ct = 0; ct < 4; ++ct) {
    int row = ct * 16 + lr, r7 = row & 7;
    #pragma unroll
    for (int kk = 0; kk < 6; ++kk) {
      s16x8 b = *(const s16x8*)&Bls[row * 192 + (((kk * 4 + lq) ^ r7) << 3)];
      acc[0][ct] = __builtin_amdgcn_mfma_f32_16x16x32_bf16(A0[kk], b, acc[0][ct], 0, 0, 0);
      acc[1][ct] = __builtin_amdgcn_mfma_f32_16x16x32_bf16(A1[kk], b, acc[1][ct], 0, 0, 0);
    }
  }

  if (PHASE == 0) {
    // per-block stats partials -> out_e (= outH scratch), NO global atomics
    float s1[4], s2[4];
    #pragma unroll
    for (int ct = 0; ct < 4; ++ct) {
      float bias = b_upd[ct * 16 + lr];
      float a1s = 0.f, a2s = 0.f;
      #pragma unroll
      for (int rt = 0; rt < 2; ++rt)
        #pragma unroll
        for (int q = 0; q < 4; ++q) {
          float v = acc[rt][ct][q] + bias;
          a1s += v; a2s += v * v;
        }
      s1[ct] = a1s; s2[ct] = a2s;
    }
    #pragma unroll
    for (int ct = 0; ct < 4; ++ct) {
      s1[ct] += __shfl_xor(s1[ct], 16); s1[ct] += __shfl_xor(s1[ct], 32);
      s2[ct] += __shfl_xor(s2[ct], 16); s2[ct] += __shfl_xor(s2[ct], 32);
    }
    if (ln < 16) {
      #pragma unroll
      for (int ct = 0; ct < 4; ++ct) {
        red[wv][ct * 16 + ln] = s1[ct];
        red[wv][64 + ct * 16 + ln] = s2[ct];
      }
    }
    __syncthreads();
    if (tid < 128) {
      float t = red[0][tid] + red[1][tid] + red[2][tid] + red[3][tid];
      out_e[(size_t)blockIdx.x * 128 + tid] = t;
    }
  } else {
    // bn+silu in frag layout (in place)
    #pragma unroll
    for (int ct = 0; ct < 4; ++ct) {
      int col = ct * 16 + lr;
      float scale = ws[128 + col], shift = ws[192 + col], bias = b_upd[col];
      #pragma unroll
      for (int rt = 0; rt < 2; ++rt)
        #pragma unroll
        for (int q = 0; q < 4; ++q) {
          float x = acc[rt][ct][q] + bias;
          acc[rt][ct][q] = siluf(x * scale + shift);
        }
    }
    __syncthreads();   // all waves done reading Bls -> reuse as transpose scratch
    float* T = (float*)((char*)Bls + wv * 1280);   // 4 rows x 72-float stride
    #pragma unroll
    for (int rt = 0; rt < 2; ++rt) {
      #pragma unroll
      for (int q = 0; q < 4; ++q) {
        #pragma unroll
        for (int ct = 0; ct < 4; ++ct)
          T[lq * 72 + ct * 16 + lr] = acc[rt][ct][q];
        float4 t4 = *(const float4*)&T[rl * 72 + c0];
        float4 ev = epre[rt][q];
        t4.x += ev.x; t4.y += ev.y; t4.z += ev.z; t4.w += ev.w;
        ntstore4(&out_e[(size_t)(m0 + wv * 32 + rt * 16 + rl * 4 + q) * 64 + c0], t4);
      }
    }
  }
}

// ---------------- fused reduce + finalize edge-BN stats: 64 blocks, one per feature ----------------
__global__ void k_redfin(const float* __restrict__ partials, float* __restrict__ ws,
                         const float* __restrict__ gamma, const float* __restrict__ beta,
                         float rcount) {
  __shared__ float sr[2][256];
  int c = blockIdx.x;   // 0..63
  float s1 = 0.f, s2 = 0.f;
  for (int i = threadIdx.x; i < EBLK; i += 256) {
    s1 += partials[(size_t)i * 128 + c];
    s2 += partials[(size_t)i * 128 + 64 + c];
  }
  sr[0][threadIdx.x] = s1; sr[1][threadIdx.x] = s2;
  __syncthreads();
  for (int off = 128; off >= 1; off >>= 1) {
    if (threadIdx.x < off) {
      sr[0][threadIdx.x] += sr[0][threadIdx.x + off];
      sr[1][threadIdx.x] += sr[1][threadIdx.x + off];
    }
    __syncthreads();
  }
  if (threadIdx.x == 0) {
    float mean = sr[0][0] * rcount;
    float var = sr[1][0] * rcount - mean * mean;
    float a = rsqrtf(var + EPS_BN) * gamma[c];
    ws[128 + c] = a;
    ws[192 + c] = beta[c] - mean * a;
  }
}

// ---------------- node output: inline BN-finalize; t = silu(bn(v)) + h; out = t@W_out.T + b ----------------
__global__ __launch_bounds__(256, 4) void k_nout(
    const float* __restrict__ h, const unsigned int* __restrict__ wsu,
    const float* __restrict__ g_gn, const float* __restrict__ be_gn,
    const float* __restrict__ b_out, const float* __restrict__ ws,
    const float* __restrict__ v_in, float* __restrict__ out_h)
{
  __shared__ short R1[128 * 64];   // t-tile, swizzled
  __shared__ short R2[64 * 64];    // W_out, swizzled
  __shared__ float sA[64], sB[64];
  int tid = threadIdx.x;
  int ln = tid & 63, wv = tid >> 6;
  int lr = ln & 15, lq = ln >> 4;
  int n0 = blockIdx.x * 128;

  const uint4* Sot = (const uint4*)(wsu + 10752);
  #pragma unroll
  for (int j = 0; j < 2; ++j) {
    int c = tid + j * 256;
    int row = c >> 3, i = c & 7, sl = row * 8 + (i ^ (row & 7));
    ((uint4*)R2)[sl] = Sot[c];
  }
  // inline finalize of node BN scale/shift (redundant per block, cheap)
  if (tid < 64) {
    float mean = ws[256 + tid] * (1.f / (float)N_NODES);
    float var = ws[320 + tid] * (1.f / (float)N_NODES) - mean * mean;
    float a = rsqrtf(var + EPS_BN) * g_gn[tid];
    sA[tid] = a;
    sB[tid] = be_gn[tid] - mean * a;
  }
  __syncthreads();

  // row-layout: coalesced float4 reads of v and h; BN+silu+residual; bf16 into R1
  int c0 = (tid & 15) * 4;
  int rbase = tid >> 4;   // 0..15
  float4 scl = *(const float4*)&sA[c0];
  float4 shf = *(const float4*)&sB[c0];
  #pragma unroll
  for (int i = 0; i < 8; ++i) {
    int row = rbase + 16 * i;
    int n = min(n0 + row, N_NODES - 1);
    float4 v4 = *(const float4*)&v_in[(size_t)n * 64 + c0];
    float4 h4 = *(const float4*)&h[(size_t)n * 64 + c0];
    float tx = siluf(v4.x * scl.x + shf.x) + h4.x;
    float ty = siluf(v4.y * scl.y + shf.y) + h4.y;
    float tz = siluf(v4.z * scl.z + shf.z) + h4.z;
    float tw = siluf(v4.w * scl.w + shf.w) + h4.w;
    int sl = ((((c0 >> 3) ^ (row & 7)) << 3) | (c0 & 7));
    unsigned int* p = (unsigned int*)&R1[row * 64 + sl];
    p[0] = pack2(tx, ty);
    p[1] = pack2(tz, tw);
  }
  __syncthreads();

  int r0 = wv * 32 + lr, r1 = r0 + 16;
  s16x8 T0[2], T1[2];
  #pragma unroll
  for (int kk = 0; kk < 2; ++kk) {
    T0[kk] = *(const s16x8*)&R1[r0 * 64 + (((kk * 4 + lq) ^ (r0 & 7)) << 3)];
    T1[kk] = *(const s16x8*)&R1[r1 * 64 + (((kk * 4 + lq) ^ (r1 & 7)) << 3)];
  }
  f32x4 zero4 = {0.f, 0.f, 0.f, 0.f};
  f32x4 ac2[2][4];
  #pragma unroll
  for (int rt = 0; rt < 2; ++rt)
    #pragma unroll
    for (int ct = 0; ct < 4; ++ct) ac2[rt][ct] = zero4;
  #pragma unroll
  for (int ct = 0; ct < 4; ++ct) {
    int row = ct * 16 + lr, r7 = row & 7;
    #pragma unroll
    for (int kk = 0; kk < 2; ++kk) {
      s16x8 b = *(const s16x8*)&R2[row * 64 + (((kk * 4 + lq) ^ r7) << 3)];
      ac2[0][ct] = __builtin_amdgcn_mfma_f32_16x16x32_bf16(T0[kk], b, ac2[0][ct], 0, 0, 0);
      ac2[1][ct] = __builtin_amdgcn_mfma_f32_16x16x32_bf16(T1[kk], b, ac2[1][ct], 0, 0, 0);
    }
  }
  #pragma unroll
  for (int ct = 0; ct < 4; ++ct) {
    int col = ct * 16 + lr;
    float bo = b_out[col];
    #pragma unroll
    for (int rt = 0; rt < 2; ++rt)
      #pragma unroll
      for (int q = 0; q < 4; ++q) {
        int row = wv * 32 + rt * 16 + lq * 4 + q;
        int n = n0 + row;
        if (n < N_NODES)
          __builtin_nontemporal_store(ac2[rt][ct][q] + bo,
                                      &out_h[(size_t)n * 64 + col]);
      }
  }
}

extern "C" void kernel_launch(void* const* d_in, const int* in_sizes, int n_in,
                              void* d_out, int out_size, void* d_ws, size_t ws_size,
                              hipStream_t stream) {
  const float* h     = (const float*)d_in[0];
  const float* e     = (const float*)d_in[1];
  const int*   src   = (const int*)d_in[2];
  const int*   dst   = (const int*)d_in[3];
  const float* W_upd = (const float*)d_in[4];
  const float* b_upd = (const float*)d_in[5];
  const float* g_un  = (const float*)d_in[6];
  const float* be_un = (const float*)d_in[7];
  // d_in[8], d_in[9]: W_act, b_act -- dead (softmax weights sum to 1 per dst)
  const float* W_gd  = (const float*)d_in[10];
  const float* b_gd  = (const float*)d_in[11];
  const float* W_gs  = (const float*)d_in[12];
  const float* b_gs  = (const float*)d_in[13];
  const float* g_gn  = (const float*)d_in[14];
  const float* be_gn = (const float*)d_in[15];
  const float* W_out = (const float*)d_in[16];
  const float* b_out = (const float*)d_in[17];

  float* outH = (float*)d_out;
  float* outE = outH + (size_t)N_NODES * 64;
  float* ws = (float*)d_ws;
  unsigned int* wsu = (unsigned int*)d_ws;
  unsigned char* flb = (unsigned char*)(wsu + 12800);
  short* hbf = (short*)(wsu + 25600);

  // 1. init + h->bf16 cache
  k_pre<<<49 + 1563, 256, 0, stream>>>(wsu, W_upd, W_gd, W_gs, W_out, h, hbf);
  // 2. edge GEMM phase 0: stats partials -> outH scratch; sets flags
  k_edge<0><<<EBLK, 256, 0, stream>>>(hbf, e, src, dst, wsu, b_upd, ws, flb,
                                      nullptr, nullptr, nullptr, nullptr, outH);
  // 3. reduce+finalize edge BN
  k_redfin<<<64, 256, 0, stream>>>(outH, ws, g_un, be_un, 1.f / (float)N_EDGES);
  // 4. edge GEMM phase 1 (e2 output) + riding nstat blocks (v-spill -> outH, node sums)
  k_edge<1><<<EBLK + NBLK, 256, 0, stream>>>(hbf, e, src, dst, wsu, b_upd, ws, flb,
                                             b_gd, b_gs, ws, outH, outE);
  // 5. node output (inline BN finalize)
  k_nout<<<NBLK, 256, 0, stream>>>(h, wsu, g_gn, be_gn, b_out, ws, outH, outH);
}